// Round 13
// baseline (109.916 us; speedup 1.0000x reference)
//
#include <hip/hip_runtime.h>
#include <hip/hip_bf16.h>
#include <stdint.h>

// SketchConv2d: out = conv2d(x, Weff) + bias, where
// Weff[o,f] = (1/4) * sum_{n,s} sketches[n,f,s] * signed[n,s,o]
// f channel-major flat (c*9 + kh*3 + kw).
//
// B=32, CIN=128, H=W=64, OUT=256, KH=KW=3, H2=W2=62, NSK=4, SDIM=128.
//
// Round 13: verbatim m201 phase shape (reads BEFORE barrier -> lgkm0 hard
// gate at barrier exit -> pure 16-MFMA cluster -> pacing barrier; 2 phases
// = 4 barriers per BK=32 step; vmcnt counted, never 0 mid-loop).
// Geometry unchanged from r12: 256o x 256e block, 8 waves (2M x 4N),
// A 4-slot ring (16 KB tiles, fragment-linear, glds-staged), B resident.

#define BATCH 32
#define CIN   128
#define HH    64
#define WW    64
#define OUTC  256
#define H2    62
#define W2    62
#define A_TILE 16384                  // 256 o x 32 k x 2B per BK=32 step
#define WS_A_BYTES (36 * A_TILE)      // 576 KB
#define BROWB 16384                   // 64 j * 256 B per x-row
#define AMAX  (35 * A_TILE)

typedef __bf16 bf16x8 __attribute__((ext_vector_type(8)));
typedef float  f32x4  __attribute__((ext_vector_type(4)));

typedef unsigned int u32_as1 __attribute__((address_space(1)));
typedef unsigned int u32_as3 __attribute__((address_space(3)));

__device__ __forceinline__ void async_copy16(const void* g, void* l) {
  __builtin_amdgcn_global_load_lds((const u32_as1*)g, (u32_as3*)l, 16, 0, 0);
}

// ---------------------------------------------------------------------------
// Kernel 1 (unchanged, verified r9-r12): Weff -> 36 fragment-linear images.
// st = tap*4 + (c>>5), tap = kh*3+kw, kk = c&31:
// byte = st*16384 + (o>>4)*1024 + ((kk>>3)*16 + (o&15))*16 + (kk&7)*2
// ---------------------------------------------------------------------------
#define FPB 4
__global__ __launch_bounds__(256) void weff_kernel(
    const float* __restrict__ sketches,   // (4, 1152, 128)
    const float* __restrict__ sgn,        // (4, 128, 256)
    char* __restrict__ wsA)
{
  __shared__ alignas(16) float sk[512 * FPB];
  const int f0 = blockIdx.x * FPB;
  const int t  = threadIdx.x;

  for (int k = 0; k < (512 * FPB) / 256; ++k) {
    int idx = t + k * 256;
    int fi  = idx >> 9;
    int ns  = idx & 511;
    int n   = ns >> 7;
    int s   = ns & 127;
    sk[ns * FPB + fi] = sketches[(n * 1152 + f0 + fi) * 128 + s];
  }
  __syncthreads();

  const int o = t;
  float acc0 = 0.f, acc1 = 0.f, acc2 = 0.f, acc3 = 0.f;
#pragma unroll 8
  for (int ns = 0; ns < 512; ++ns) {
    float sg = sgn[ns * 256 + o];
    f32x4 skv = *(const f32x4*)(&sk[ns * FPB]);
    acc0 += sg * skv[0];
    acc1 += sg * skv[1];
    acc2 += sg * skv[2];
    acc3 += sg * skv[3];
  }

  float accs[FPB] = {acc0, acc1, acc2, acc3};
#pragma unroll
  for (int fi = 0; fi < FPB; ++fi) {
    int f   = f0 + fi;
    int c   = f / 9;
    int tap = f - c * 9;
    int st  = tap * 4 + (c >> 5);
    int kk  = c & 31;
    uint32_t byteoff = (uint32_t)st * A_TILE + (uint32_t)(o >> 4) * 1024
                     + (uint32_t)(((kk >> 3) * 16 + (o & 15)) * 16)
                     + (uint32_t)((kk & 7) * 2);
    *(__hip_bfloat16*)(wsA + byteoff) = __float2bfloat16(accs[fi] * 0.25f);
  }
}

// ---------------------------------------------------------------------------
// Kernel 2: implicit-GEMM conv, m201-phase-shape K-loop.
// Block (b, ig): 256 o x 256 e (4 i-rows x 64 j), 8 waves (512 thr).
// wave: wm = w>>2 (o-half of 128 rows), we = w&3 (i-row).
// ---------------------------------------------------------------------------
__global__ __launch_bounds__(512, 2) void conv_kernel(
    const float* __restrict__ x,
    const char*  __restrict__ wA,
    const float* __restrict__ bias,
    float* __restrict__ out)
{
  __shared__ alignas(16) char lds[4 * A_TILE + 6 * BROWB];  // 64 + 96 KB
  char* ldsA = lds;
  char* ldsB = lds + 4 * A_TILE;

  const int bid = blockIdx.x;
  const int swz = (bid & 7) * 64 + (bid >> 3);    // 512 = 8*64, bijective
  const int b   = swz >> 4;
  const int ig  = swz & 15;
  const int i0  = ig * 4;

  const int t    = threadIdx.x;
  const int lane = t & 63;
  const int w    = t >> 6;       // 0..7
  const int wm   = w >> 2;       // o-half (128 rows)
  const int we   = w & 3;        // i-row within group

  const char* aSrcLane = wA + w * 2048 + lane * 16;

#define STAGE(AOFF, TGT) do {                                              \
    const char* s_ = aSrcLane + (AOFF);                                    \
    char* d_ = ldsA + (TGT) * A_TILE + w * 2048;                           \
    async_copy16(s_,        d_);                                           \
    async_copy16(s_ + 1024, d_ + 1024);                                    \
  } while (0)

  // prologue: tiles 0..2 in flight across B staging
  STAGE(0, 0);
  STAGE(A_TILE, 1);
  STAGE(2 * A_TILE, 2);

  // ---- stage B once: x[b, :, i0..i0+5 (row-clamped), :] -> [r][j][c] swz
  {
    const int j  = t & 63;
    const int cq = t >> 6;                         // 8 groups of 16 channels
    const uint32_t swb = (uint32_t)((j & 7) << 4);
#pragma unroll
    for (int r = 0; r < 6; ++r) {
      int xrow = i0 + r; if (xrow > 63) xrow = 63;
      const float* xr = x + (((size_t)(b * CIN + cq * 16)) * HH + xrow) * WW + j;
      char* lrow = ldsB + r * BROWB + j * 256;
#pragma unroll
      for (int g = 0; g < 2; ++g) {
        bf16x8 pk;
#pragma unroll
        for (int cc = 0; cc < 8; ++cc)
          pk[cc] = (__bf16)xr[(size_t)(g * 8 + cc) * (HH * WW)];
        uint32_t c0b = (uint32_t)(cq * 32 + g * 16);
        *(bf16x8*)(lrow + (c0b ^ swb)) = pk;
      }
    }
  }

  f32x4 acc[8][4];
  const f32x4 zf = {0.f, 0.f, 0.f, 0.f};
#pragma unroll
  for (int mi = 0; mi < 8; ++mi)
#pragma unroll
    for (int ni = 0; ni < 4; ++ni)
      acc[mi][ni] = zf;

  // ---- per-lane LDS read bases
  const int ln15  = lane & 15;
  const int khi16 = (lane >> 4) << 4;
  const char* pA = ldsA + wm * 8192 + lane * 16;   // frag mi at +mi*1024

#define MKB(COL, PAR) (ldsB + we * BROWB + (COL) * 256                     \
    + (uint32_t)(((((PAR) * 64) | khi16) ^ (((COL) & 7) << 4))))
  const char* pB00 = MKB(ln15 + 0, 0); const char* pB01 = MKB(ln15 + 0, 1);
  const char* pB10 = MKB(ln15 + 1, 0); const char* pB11 = MKB(ln15 + 1, 1);
  const char* pB20 = MKB(ln15 + 2, 0); const char* pB21 = MKB(ln15 + 2, 1);
  const int c30 = (48 + ln15 + 0 > 63) ? 63 : 48 + ln15 + 0;
  const int c31 = (48 + ln15 + 1 > 63) ? 63 : 48 + ln15 + 1;
  const int c32 = (48 + ln15 + 2 > 63) ? 63 : 48 + ln15 + 2;
  const char* pC00 = MKB(c30, 0); const char* pC01 = MKB(c30, 1);
  const char* pC10 = MKB(c31, 0); const char* pC11 = MKB(c31, 1);
  const char* pC20 = MKB(c32, 0); const char* pC21 = MKB(c32, 1);
#undef MKB

  __syncthreads();   // drains tiles 0-2 (vmcnt0) + all B ds_writes, publishes

  bf16x8 aL0, aL1, aL2, aL3, aH0, aH1, aH2, aH3, b0, b1, b2, b3;
  uint32_t aoff = 3 * A_TILE;    // next tile to stage

#define MFMA_ __builtin_amdgcn_mfma_f32_16x16x32_bf16
#define VM4   asm volatile("s_waitcnt vmcnt(4)" ::: "memory")
#define LGKM0 asm volatile("s_waitcnt lgkmcnt(0)" ::: "memory")
#define SB0   __builtin_amdgcn_sched_barrier(0)

#define MFMA16(A0_, A1_, A2_, A3_, M_) do {                                \
    __builtin_amdgcn_s_setprio(1);                                         \
    acc[(M_)+0][0] = MFMA_(A0_, b0, acc[(M_)+0][0], 0, 0, 0);              \
    acc[(M_)+0][1] = MFMA_(A0_, b1, acc[(M_)+0][1], 0, 0, 0);              \
    acc[(M_)+0][2] = MFMA_(A0_, b2, acc[(M_)+0][2], 0, 0, 0);              \
    acc[(M_)+0][3] = MFMA_(A0_, b3, acc[(M_)+0][3], 0, 0, 0);              \
    acc[(M_)+1][0] = MFMA_(A1_, b0, acc[(M_)+1][0], 0, 0, 0);              \
    acc[(M_)+1][1] = MFMA_(A1_, b1, acc[(M_)+1][1], 0, 0, 0);              \
    acc[(M_)+1][2] = MFMA_(A1_, b2, acc[(M_)+1][2], 0, 0, 0);              \
    acc[(M_)+1][3] = MFMA_(A1_, b3, acc[(M_)+1][3], 0, 0, 0);              \
    acc[(M_)+2][0] = MFMA_(A2_, b0, acc[(M_)+2][0], 0, 0, 0);              \
    acc[(M_)+2][1] = MFMA_(A2_, b1, acc[(M_)+2][1], 0, 0, 0);              \
    acc[(M_)+2][2] = MFMA_(A2_, b2, acc[(M_)+2][2], 0, 0, 0);              \
    acc[(M_)+2][3] = MFMA_(A2_, b3, acc[(M_)+2][3], 0, 0, 0);              \
    acc[(M_)+3][0] = MFMA_(A3_, b0, acc[(M_)+3][0], 0, 0, 0);              \
    acc[(M_)+3][1] = MFMA_(A3_, b1, acc[(M_)+3][1], 0, 0, 0);              \
    acc[(M_)+3][2] = MFMA_(A3_, b2, acc[(M_)+3][2], 0, 0, 0);              \
    acc[(M_)+3][3] = MFMA_(A3_, b3, acc[(M_)+3][3], 0, 0, 0);              \
    __builtin_amdgcn_s_setprio(0);                                         \
  } while (0)

  // one BK=32 step, two m201-shaped phases (reads BEFORE barrier; lgkm0
  // hard gate after; pure MFMA cluster; pacing barrier).
  // WAR: STAGE target (Q+3)&3 == (Q-1)&3, whose last reads (phase B of
  // step Q-1) completed before that step's final barrier.
  // Publish: vmcnt(4) completes stage(s+1); tile s was certified last step.
#define STEPQ(Q, KW, PAR, CK2) do {                                        \
    aL0 = *(const bf16x8*)(pA + (Q & 3) * A_TILE);                         \
    aL1 = *(const bf16x8*)(pA + (Q & 3) * A_TILE + 1024);                  \
    aL2 = *(const bf16x8*)(pA + (Q & 3) * A_TILE + 2048);                  \
    aL3 = *(const bf16x8*)(pA + (Q & 3) * A_TILE + 3072);                  \
    b0 = *(const bf16x8*)(pB##KW##PAR + (CK2) * 128);                      \
    b1 = *(const bf16x8*)(pB##KW##PAR + (CK2) * 128 + 4096);               \
    b2 = *(const bf16x8*)(pB##KW##PAR + (CK2) * 128 + 8192);               \
    b3 = *(const bf16x8*)(pC##KW##PAR + (CK2) * 128);                      \
    STAGE(aoff, (Q + 3) & 3);                                              \
    aoff += A_TILE; if (aoff > AMAX) aoff = AMAX;                          \
    VM4;                                                                   \
    __builtin_amdgcn_s_barrier();                                          \
    LGKM0; SB0;                                                            \
    MFMA16(aL0, aL1, aL2, aL3, 0);                                         \
    __builtin_amdgcn_s_barrier();                                          \
    aH0 = *(const bf16x8*)(pA + (Q & 3) * A_TILE + 4096);                  \
    aH1 = *(const bf16x8*)(pA + (Q & 3) * A_TILE + 5120);                  \
    aH2 = *(const bf16x8*)(pA + (Q & 3) * A_TILE + 6144);                  \
    aH3 = *(const bf16x8*)(pA + (Q & 3) * A_TILE + 7168);                  \
    __builtin_amdgcn_s_barrier();                                          \
    LGKM0; SB0;                                                            \
    MFMA16(aH0, aH1, aH2, aH3, 4);                                         \
    __builtin_amdgcn_s_barrier();                                          \
  } while (0)

#pragma unroll 1
  for (int kh = 0; kh < 3; ++kh) {
    STEPQ(0,  0, 0, 0);
    STEPQ(1,  0, 1, 0);
    STEPQ(2,  0, 0, 1);
    STEPQ(3,  0, 1, 1);
    STEPQ(4,  1, 0, 0);
    STEPQ(5,  1, 1, 0);
    STEPQ(6,  1, 0, 1);
    STEPQ(7,  1, 1, 1);
    STEPQ(8,  2, 0, 0);
    STEPQ(9,  2, 1, 0);
    STEPQ(10, 2, 0, 1);
    STEPQ(11, 2, 1, 1);
    if (kh < 2) {
      pB00 += BROWB; pB01 += BROWB; pB10 += BROWB; pB11 += BROWB;
      pB20 += BROWB; pB21 += BROWB; pC00 += BROWB; pC01 += BROWB;
      pC10 += BROWB; pC11 += BROWB; pC20 += BROWB; pC21 += BROWB;
    }
  }

#undef STEPQ
#undef MFMA16
#undef SB0
#undef LGKM0
#undef VM4
#undef MFMA_
#undef STAGE

  // ---- epilogue: D[m][n]: m=(lane>>4)*4+reg, n=lane&15
  const int jn   = ln15;
  const int g4   = lane >> 4;
  const int irow = i0 + we;
  if (irow < H2) {
#pragma unroll
    for (int mi = 0; mi < 8; ++mi) {
#pragma unroll
      for (int ni = 0; ni < 4; ++ni) {
        const int jj = (ni << 4) + jn;
        if (jj < W2) {
#pragma unroll
          for (int rr = 0; rr < 4; ++rr) {
            const int o = (wm << 7) + (mi << 4) + (g4 << 2) + rr;
            out[(((size_t)b * OUTC + o) * H2 + irow) * W2 + jj] =
                acc[mi][ni][rr] + bias[o];
          }
        }
      }
    }
  }
}

extern "C" void kernel_launch(void* const* d_in, const int* in_sizes, int n_in,
                              void* d_out, int out_size, void* d_ws, size_t ws_size,
                              hipStream_t stream) {
  const float* x        = (const float*)d_in[0];
  const float* sketches = (const float*)d_in[1];
  const float* sgn      = (const float*)d_in[2];
  const float* bias     = (const float*)d_in[3];
  float* out            = (float*)d_out;
  char* wsA             = (char*)d_ws;

  if (ws_size < (size_t)WS_A_BYTES) return;  // need 576 KB scratch

  weff_kernel<<<1152 / FPB, 256, 0, stream>>>(sketches, sgn, wsA);
  conv_kernel<<<BATCH * 16, 512, 0, stream>>>(x, wsA, bias, out);
}

// Round 14
// 106.459 us; speedup vs baseline: 1.0325x; 1.0325x over previous
//
#include <hip/hip_runtime.h>
#include <hip/hip_bf16.h>
#include <stdint.h>

// SketchConv2d: out = conv2d(x, Weff) + bias, where
// Weff[o,f] = (1/4) * sum_{n,s} sketches[n,f,s] * signed[n,s,o]
// f channel-major flat (c*9 + kh*3 + kw).
//
// B=32, CIN=128, H=W=64, OUT=256, KH=KW=3, H2=W2=62, NSK=4, SDIM=128.
//
// Round 14: OCCUPANCY, not schedule. r4-r13 all ran 2 waves/SIMD; every
// schedule variant tied at 29-31% MfmaUtil because intra-wave serial
// latency (ds_read->lgkm->MFMA) has no TLP cover at 2 waves/SIMD.
// This round: same 256o x 256e block, 16 waves of 64o x 64e
// (__launch_bounds__(1024,4) -> 4 waves/SIMD, acc only 64 VGPR/wave),
// r7-proven simple 2-phase schedule (stage-at-top, one __syncthreads).
// A ring 4 x 16 KB (r13 layout, verified) + B 6 rows 96 KB = 160 KB.

#define BATCH 32
#define CIN   128
#define HH    64
#define WW    64
#define OUTC  256
#define H2    62
#define W2    62
#define A_TILE 16384                  // 256 o x 32 k x 2B per BK=32 step
#define WS_A_BYTES (36 * A_TILE)      // 576 KB
#define BROWB 16384                   // 64 j * 256 B per x-row
#define AMAX  (35 * A_TILE)

typedef __bf16 bf16x8 __attribute__((ext_vector_type(8)));
typedef float  f32x4  __attribute__((ext_vector_type(4)));

typedef unsigned int u32_as1 __attribute__((address_space(1)));
typedef unsigned int u32_as3 __attribute__((address_space(3)));

__device__ __forceinline__ void async_copy16(const void* g, void* l) {
  __builtin_amdgcn_global_load_lds((const u32_as1*)g, (u32_as3*)l, 16, 0, 0);
}

// ---------------------------------------------------------------------------
// Kernel 1 (unchanged, verified r9-r13): Weff -> 36 fragment-linear images.
// st = tap*4 + (c>>5), tap = kh*3+kw, kk = c&31:
// byte = st*16384 + (o>>4)*1024 + ((kk>>3)*16 + (o&15))*16 + (kk&7)*2
// ---------------------------------------------------------------------------
#define FPB 4
__global__ __launch_bounds__(256) void weff_kernel(
    const float* __restrict__ sketches,   // (4, 1152, 128)
    const float* __restrict__ sgn,        // (4, 128, 256)
    char* __restrict__ wsA)
{
  __shared__ alignas(16) float sk[512 * FPB];
  const int f0 = blockIdx.x * FPB;
  const int t  = threadIdx.x;

  for (int k = 0; k < (512 * FPB) / 256; ++k) {
    int idx = t + k * 256;
    int fi  = idx >> 9;
    int ns  = idx & 511;
    int n   = ns >> 7;
    int s   = ns & 127;
    sk[ns * FPB + fi] = sketches[(n * 1152 + f0 + fi) * 128 + s];
  }
  __syncthreads();

  const int o = t;
  float acc0 = 0.f, acc1 = 0.f, acc2 = 0.f, acc3 = 0.f;
#pragma unroll 8
  for (int ns = 0; ns < 512; ++ns) {
    float sg = sgn[ns * 256 + o];
    f32x4 skv = *(const f32x4*)(&sk[ns * FPB]);
    acc0 += sg * skv[0];
    acc1 += sg * skv[1];
    acc2 += sg * skv[2];
    acc3 += sg * skv[3];
  }

  float accs[FPB] = {acc0, acc1, acc2, acc3};
#pragma unroll
  for (int fi = 0; fi < FPB; ++fi) {
    int f   = f0 + fi;
    int c   = f / 9;
    int tap = f - c * 9;
    int st  = tap * 4 + (c >> 5);
    int kk  = c & 31;
    uint32_t byteoff = (uint32_t)st * A_TILE + (uint32_t)(o >> 4) * 1024
                     + (uint32_t)(((kk >> 3) * 16 + (o & 15)) * 16)
                     + (uint32_t)((kk & 7) * 2);
    *(__hip_bfloat16*)(wsA + byteoff) = __float2bfloat16(accs[fi] * 0.25f);
  }
}

// ---------------------------------------------------------------------------
// Kernel 2: implicit-GEMM conv, 16 waves / 4 per SIMD.
// Block (b, ig): 256 o x 256 e (4 i-rows x 64 j), 1024 threads.
// wave: wo = w>>2 (o-quarter, 64 rows), we = w&3 (i-row).
// ---------------------------------------------------------------------------
__global__ __launch_bounds__(1024, 4) void conv_kernel(
    const float* __restrict__ x,
    const char*  __restrict__ wA,
    const float* __restrict__ bias,
    float* __restrict__ out)
{
  __shared__ alignas(16) char lds[4 * A_TILE + 6 * BROWB];  // 64 + 96 KB
  char* ldsA = lds;
  char* ldsB = lds + 4 * A_TILE;

  const int bid = blockIdx.x;
  const int swz = (bid & 7) * 64 + (bid >> 3);    // 512 = 8*64, bijective
  const int b   = swz >> 4;
  const int ig  = swz & 15;
  const int i0  = ig * 4;

  const int t    = threadIdx.x;
  const int lane = t & 63;
  const int w    = t >> 6;       // 0..15
  const int wo   = w >> 2;       // o-quarter (64 rows)
  const int we   = w & 3;        // i-row within group

  const char* aSrcLane = wA + w * 1024 + lane * 16;

  // one 16 KB tile = 1 async_copy16 per wave (16 waves x 1 KB)
#define STAGE(AOFF, TGT) do {                                              \
    async_copy16(aSrcLane + (AOFF), ldsA + (TGT) * A_TILE + w * 1024);     \
  } while (0)

  // prologue: tiles 0..2 in flight across B staging
  STAGE(0, 0);
  STAGE(A_TILE, 1);
  STAGE(2 * A_TILE, 2);

  // ---- stage B once: x[b, :, i0..i0+5 (row-clamped), :] -> [r][j][c] swz
  {
    const int j  = t & 63;
    const int cq = t >> 6;                         // 16 groups of 8 channels
    const uint32_t swb = (uint32_t)((j & 7) << 4);
#pragma unroll
    for (int r = 0; r < 6; ++r) {
      int xrow = i0 + r; if (xrow > 63) xrow = 63;
      const float* xr = x + (((size_t)(b * CIN + cq * 8)) * HH + xrow) * WW + j;
      bf16x8 pk;
#pragma unroll
      for (int cc = 0; cc < 8; ++cc)
        pk[cc] = (__bf16)xr[(size_t)cc * (HH * WW)];
      *(bf16x8*)(ldsB + r * BROWB + j * 256 + (((uint32_t)cq * 16u) ^ swb)) = pk;
    }
  }

  f32x4 acc[4][4];
  const f32x4 zf = {0.f, 0.f, 0.f, 0.f};
#pragma unroll
  for (int mi = 0; mi < 4; ++mi)
#pragma unroll
    for (int ni = 0; ni < 4; ++ni)
      acc[mi][ni] = zf;

  // ---- per-lane LDS read bases
  const int ln15  = lane & 15;
  const int khi16 = (lane >> 4) << 4;
  const char* pA = ldsA + wo * 4096 + lane * 16;   // frag mi at +mi*1024

#define MKB(COL, PAR) (ldsB + we * BROWB + (COL) * 256                     \
    + (uint32_t)(((((PAR) * 64) | khi16) ^ (((COL) & 7) << 4))))
  const char* pB00 = MKB(ln15 + 0, 0); const char* pB01 = MKB(ln15 + 0, 1);
  const char* pB10 = MKB(ln15 + 1, 0); const char* pB11 = MKB(ln15 + 1, 1);
  const char* pB20 = MKB(ln15 + 2, 0); const char* pB21 = MKB(ln15 + 2, 1);
  const int c30 = (48 + ln15 + 0 > 63) ? 63 : 48 + ln15 + 0;
  const int c31 = (48 + ln15 + 1 > 63) ? 63 : 48 + ln15 + 1;
  const int c32 = (48 + ln15 + 2 > 63) ? 63 : 48 + ln15 + 2;
  const char* pC00 = MKB(c30, 0); const char* pC01 = MKB(c30, 1);
  const char* pC10 = MKB(c31, 0); const char* pC11 = MKB(c31, 1);
  const char* pC20 = MKB(c32, 0); const char* pC21 = MKB(c32, 1);
#undef MKB

  __syncthreads();   // drains tiles 0-2 (vmcnt0) + all B ds_writes, publishes

  uint32_t aoff = 3 * A_TILE;    // next tile to stage

#define MFMA_ __builtin_amdgcn_mfma_f32_16x16x32_bf16

  // one BK=32 step: stage(s+3) at top (3 steps of flight), 4 A + 4 B
  // ds_reads, 16 MFMA, __syncthreads (publish + WAR). 4 waves/SIMD cover
  // the lgkm/drain latency.
#define STEPQ(Q, KW, PAR, CK2) do {                                        \
    STAGE(aoff, (Q + 3) & 3);                                              \
    aoff += A_TILE; if (aoff > AMAX) aoff = AMAX;                          \
    bf16x8 a0_ = *(const bf16x8*)(pA + (Q & 3) * A_TILE);                  \
    bf16x8 a1_ = *(const bf16x8*)(pA + (Q & 3) * A_TILE + 1024);           \
    bf16x8 a2_ = *(const bf16x8*)(pA + (Q & 3) * A_TILE + 2048);           \
    bf16x8 a3_ = *(const bf16x8*)(pA + (Q & 3) * A_TILE + 3072);           \
    bf16x8 b0_ = *(const bf16x8*)(pB##KW##PAR + (CK2) * 128);              \
    bf16x8 b1_ = *(const bf16x8*)(pB##KW##PAR + (CK2) * 128 + 4096);       \
    bf16x8 b2_ = *(const bf16x8*)(pB##KW##PAR + (CK2) * 128 + 8192);       \
    bf16x8 b3_ = *(const bf16x8*)(pC##KW##PAR + (CK2) * 128);              \
    __builtin_amdgcn_s_setprio(1);                                         \
    acc[0][0] = MFMA_(a0_, b0_, acc[0][0], 0, 0, 0);                       \
    acc[0][1] = MFMA_(a0_, b1_, acc[0][1], 0, 0, 0);                       \
    acc[0][2] = MFMA_(a0_, b2_, acc[0][2], 0, 0, 0);                       \
    acc[0][3] = MFMA_(a0_, b3_, acc[0][3], 0, 0, 0);                       \
    acc[1][0] = MFMA_(a1_, b0_, acc[1][0], 0, 0, 0);                       \
    acc[1][1] = MFMA_(a1_, b1_, acc[1][1], 0, 0, 0);                       \
    acc[1][2] = MFMA_(a1_, b2_, acc[1][2], 0, 0, 0);                       \
    acc[1][3] = MFMA_(a1_, b3_, acc[1][3], 0, 0, 0);                       \
    acc[2][0] = MFMA_(a2_, b0_, acc[2][0], 0, 0, 0);                       \
    acc[2][1] = MFMA_(a2_, b1_, acc[2][1], 0, 0, 0);                       \
    acc[2][2] = MFMA_(a2_, b2_, acc[2][2], 0, 0, 0);                       \
    acc[2][3] = MFMA_(a2_, b3_, acc[2][3], 0, 0, 0);                       \
    acc[3][0] = MFMA_(a3_, b0_, acc[3][0], 0, 0, 0);                       \
    acc[3][1] = MFMA_(a3_, b1_, acc[3][1], 0, 0, 0);                       \
    acc[3][2] = MFMA_(a3_, b2_, acc[3][2], 0, 0, 0);                       \
    acc[3][3] = MFMA_(a3_, b3_, acc[3][3], 0, 0, 0);                       \
    __builtin_amdgcn_s_setprio(0);                                         \
    __syncthreads();                                                       \
  } while (0)

#pragma unroll 1
  for (int kh = 0; kh < 3; ++kh) {
    STEPQ(0,  0, 0, 0);
    STEPQ(1,  0, 1, 0);
    STEPQ(2,  0, 0, 1);
    STEPQ(3,  0, 1, 1);
    STEPQ(4,  1, 0, 0);
    STEPQ(5,  1, 1, 0);
    STEPQ(6,  1, 0, 1);
    STEPQ(7,  1, 1, 1);
    STEPQ(8,  2, 0, 0);
    STEPQ(9,  2, 1, 0);
    STEPQ(10, 2, 0, 1);
    STEPQ(11, 2, 1, 1);
    if (kh < 2) {
      pB00 += BROWB; pB01 += BROWB; pB10 += BROWB; pB11 += BROWB;
      pB20 += BROWB; pB21 += BROWB; pC00 += BROWB; pC01 += BROWB;
      pC10 += BROWB; pC11 += BROWB; pC20 += BROWB; pC21 += BROWB;
    }
  }

#undef STEPQ
#undef MFMA_
#undef STAGE

  // ---- epilogue: D[m][n]: m=(lane>>4)*4+reg, n=lane&15
  const int jn   = ln15;
  const int g4   = lane >> 4;
  const int irow = i0 + we;
  if (irow < H2) {
#pragma unroll
    for (int mi = 0; mi < 4; ++mi) {
#pragma unroll
      for (int ni = 0; ni < 4; ++ni) {
        const int jj = (ni << 4) + jn;
        if (jj < W2) {
#pragma unroll
          for (int rr = 0; rr < 4; ++rr) {
            const int o = (wo << 6) + (mi << 4) + (g4 << 2) + rr;
            out[(((size_t)b * OUTC + o) * H2 + irow) * W2 + jj] =
                acc[mi][ni][rr] + bias[o];
          }
        }
      }
    }
  }
}

extern "C" void kernel_launch(void* const* d_in, const int* in_sizes, int n_in,
                              void* d_out, int out_size, void* d_ws, size_t ws_size,
                              hipStream_t stream) {
  const float* x        = (const float*)d_in[0];
  const float* sketches = (const float*)d_in[1];
  const float* sgn      = (const float*)d_in[2];
  const float* bias     = (const float*)d_in[3];
  float* out            = (float*)d_out;
  char* wsA             = (char*)d_ws;

  if (ws_size < (size_t)WS_A_BYTES) return;  // need 576 KB scratch

  weff_kernel<<<1152 / FPB, 256, 0, stream>>>(sketches, sgn, wsA);
  conv_kernel<<<BATCH * 16, 1024, 0, stream>>>(x, wsA, bias, out);
}